// Round 7
// baseline (1339.445 us; speedup 1.0000x reference)
//
#include <hip/hip_runtime.h>
#include <hip/hip_bf16.h>
#include <math.h>

// Problem constants (from reference)
#define E_EDGES 200000
#define TD      256      // TOKEN_DIM
#define AD      512      // ACTION_DIM
#define M_TILE  64
#define N_WG    3125     // E / M_TILE exactly

// Weight workspace layout (in shorts): hi buffer then lo buffer.
//   Wr: [0, 65536)  Wn: [65536, 131072)  W1: [131072, 393216)  W2: [393216, 655360)
// Each matrix stored as MFMA B-fragment blobs: for (ntile, kstep):
//   lane l, elem i (0..7) = W[ntile*16 + (l&15)][kstep*32 + 8*(l>>4) + i]
// at short offset base + ((ntile*KS + kstep)*64 + l)*8 + i.
// Requires ws_size >= 2*655360*2 = 2.62 MB.

using short8  = __attribute__((ext_vector_type(8))) short;
using short4v = __attribute__((ext_vector_type(4))) short;
using f32x4   = __attribute__((ext_vector_type(4))) float;

__device__ __forceinline__ unsigned short f2bf(float x) {
    unsigned u = __float_as_uint(x);
    unsigned r = (u + 0x7fffu + ((u >> 16) & 1u)) >> 16;
    return (unsigned short)r;
}
__device__ __forceinline__ float bf2f(unsigned short h) {
    return __uint_as_float(((unsigned)h) << 16);
}

// byte offset into a [64][512]-short LDS tile, XOR-swizzled so that 16-lane
// column reads (row stride 1024B) spread across all 32 banks (G4 fix).
__device__ __forceinline__ unsigned swz(int r, int c) {
    return (unsigned)((r * 512 + c) * 2) ^ (unsigned)((r & 7) << 4);
}

// ---------------------------------------------------------------------------
// Prep: fp32 weights -> bf16 hi/lo, pre-swizzled fragment layout in ws.
// 81920 blobs of 8 shorts each.
__global__ void prep_weights(const float* __restrict__ Wr, const float* __restrict__ Wn,
                             const float* __restrict__ W1, const float* __restrict__ W2,
                             short* __restrict__ whi, short* __restrict__ wlo) {
    int j = blockIdx.x * blockDim.x + threadIdx.x;
    if (j >= 81920) return;
    const float* W;
    int base_s, K, bj;
    if (j < 8192)       { W = Wr; base_s = 0;      K = 256; bj = j; }
    else if (j < 16384) { W = Wn; base_s = 65536;  K = 256; bj = j - 8192; }
    else if (j < 49152) { W = W1; base_s = 131072; K = 512; bj = j - 16384; }
    else                { W = W2; base_s = 393216; K = 512; bj = j - 49152; }
    int KS = K / 32;
    int l = bj & 63;
    int t = bj >> 6;
    int ks = t % KS;
    int ntile = t / KS;
    int n  = ntile * 16 + (l & 15);
    int kb = ks * 32 + 8 * (l >> 4);
    int off = base_s + bj * 8;   // == base_s + ((ntile*KS+ks)*64 + l)*8
#pragma unroll
    for (int i = 0; i < 8; ++i) {
        float x = W[(size_t)n * K + kb + i];
        unsigned short h  = f2bf(x);
        unsigned short lo = f2bf(x - bf2f(h));
        whi[off + i] = (short)h;
        wlo[off + i] = (short)lo;
    }
}

// ---------------------------------------------------------------------------
// One GEMM phase: acc += X_lds @ W^T using 3-product bf16 split.
// X hi at smem[0..64K), X lo at smem[64K..128K).
template <int KSTEPS>
__device__ __forceinline__ void gemm_accum(const char* smem, int xk_off,
                                           const short* __restrict__ bhi,
                                           const short* __restrict__ blo,
                                           int ntile_base, int lane,
                                           f32x4 acc[4][4]) {
    const short* pbh = bhi + (size_t)ntile_base * KSTEPS * 512 + (size_t)lane * 8;
    const short* pbl = blo + (size_t)ntile_base * KSTEPS * 512 + (size_t)lane * 8;
    for (int ks = 0; ks < KSTEPS; ++ks) {
        short8 ah[4], al[4];
        int kb = xk_off + ks * 32 + 8 * (lane >> 4);
#pragma unroll
        for (int i = 0; i < 4; ++i) {
            int row = 16 * i + (lane & 15);
            unsigned off = swz(row, kb);
            ah[i] = *(const short8*)(smem + off);
            al[i] = *(const short8*)(smem + 65536 + off);
        }
        short8 bh[4], bl[4];
#pragma unroll
        for (int j = 0; j < 4; ++j) {
            size_t wo = ((size_t)j * KSTEPS + ks) * 512;
            bh[j] = *(const short8*)(pbh + wo);
            bl[j] = *(const short8*)(pbl + wo);
        }
#pragma unroll
        for (int i = 0; i < 4; ++i) {
#pragma unroll
            for (int j = 0; j < 4; ++j) {
                acc[i][j] = __builtin_amdgcn_mfma_f32_16x16x32_bf16(ah[i], bh[j], acc[i][j], 0, 0, 0);
                acc[i][j] = __builtin_amdgcn_mfma_f32_16x16x32_bf16(ah[i], bl[j], acc[i][j], 0, 0, 0);
                acc[i][j] = __builtin_amdgcn_mfma_f32_16x16x32_bf16(al[i], bh[j], acc[i][j], 0, 0, 0);
            }
        }
    }
}

// Convert accumulators to hi/lo and store into LDS (C/D layout: col=lane&15,
// row=(lane>>4)*4+reg — m89-verified). Optional exact GELU first.
__device__ __forceinline__ void store_hilo(char* smem, int lane, int w,
                                           f32x4 acc[4][4], bool do_gelu) {
#pragma unroll
    for (int i = 0; i < 4; ++i) {
#pragma unroll
        for (int j = 0; j < 4; ++j) {
#pragma unroll
            for (int r = 0; r < 4; ++r) {
                float v = acc[i][j][r];
                if (do_gelu) v = 0.5f * v * (1.0f + erff(v * 0.7071067811865476f));
                int row = 16 * i + 4 * (lane >> 4) + r;
                int col = 64 * w + 16 * j + (lane & 15);
                unsigned short h  = f2bf(v);
                unsigned short lo = f2bf(v - bf2f(h));
                unsigned off = swz(row, col);
                *(unsigned short*)(smem + off)         = h;
                *(unsigned short*)(smem + 65536 + off) = lo;
            }
        }
    }
}

// ---------------------------------------------------------------------------
// Static LDS: 128 KiB X/activation hi+lo tile + 64 tail indices.
// (Static, not dynamic: >64KB dynamic LDS requires hipFuncSetAttribute;
//  static up to 160 KiB is allowed on gfx950.)
__global__ __launch_bounds__(512, 2) void fused_kernel(
    const float* __restrict__ rel, const float* __restrict__ nodes,
    const int* __restrict__ eidx, const short* __restrict__ whi,
    const short* __restrict__ wlo, const float* __restrict__ b1,
    const float* __restrict__ b2, float* __restrict__ out) {
    __shared__ __align__(16) char smem[131072];
    __shared__ int s_tail[64];
    const int tid  = threadIdx.x;
    const int tile = blockIdx.x;
    const int lane = tid & 63;
    const int w    = tid >> 6;

    if (tid < 64) s_tail[tid] = eidx[E_EDGES + tile * 64 + tid];
    __syncthreads();

    // P0: stage X = [R | gathered node] as bf16 hi/lo in LDS (swizzled).
#pragma unroll
    for (int c = 0; c < 16; ++c) {
        int g    = c * 512 + tid;
        int row  = g >> 7;        // 128 float4 per 512-col row
        int cf4  = g & 127;
        int e    = tile * 64 + row;
        float4 v;
        int col;
        if (cf4 < 64) {
            v   = *(const float4*)(rel + (size_t)e * TD + cf4 * 4);
            col = cf4 * 4;
        } else {
            int tail = s_tail[row];
            v   = *(const float4*)(nodes + (size_t)tail * TD + (cf4 - 64) * 4);
            col = 256 + (cf4 - 64) * 4;
        }
        float vv[4] = {v.x, v.y, v.z, v.w};
        short4v hv, lv;
#pragma unroll
        for (int t = 0; t < 4; ++t) {
            unsigned short hh = f2bf(vv[t]);
            hv[t] = (short)hh;
            lv[t] = (short)f2bf(vv[t] - bf2f(hh));
        }
        unsigned off = swz(row, col);
        *(short4v*)(smem + off)         = hv;
        *(short4v*)(smem + 65536 + off) = lv;
    }
    __syncthreads();

    // P1: layer 0 — ak[:,0:256)=R@Wr^T (waves 0-3), ak[:,256:512)=G@Wn^T (waves 4-7)
    f32x4 acc[4][4];
#pragma unroll
    for (int i = 0; i < 4; ++i)
#pragma unroll
        for (int j = 0; j < 4; ++j) acc[i][j] = (f32x4){0.f, 0.f, 0.f, 0.f};

    {
        int xoff = (w < 4) ? 0 : 256;
        const short* l0h = whi + ((w < 4) ? 0 : 65536);
        const short* l0l = wlo + ((w < 4) ? 0 : 65536);
        gemm_accum<8>(smem, xoff, l0h, l0l, 4 * (w & 3), lane, acc);
    }
    __syncthreads();                    // everyone done reading X
    store_hilo(smem, lane, w, acc, false);
    __syncthreads();                    // ak(hi/lo) ready

    // P3: layer 1 — h = gelu(ak @ W1^T + b1)
    {
        float b1v[4];
#pragma unroll
        for (int j = 0; j < 4; ++j) b1v[j] = b1[64 * w + 16 * j + (lane & 15)];
#pragma unroll
        for (int i = 0; i < 4; ++i)
#pragma unroll
            for (int j = 0; j < 4; ++j)
                acc[i][j] = (f32x4){b1v[j], b1v[j], b1v[j], b1v[j]};
        gemm_accum<16>(smem, 0, whi + 131072, wlo + 131072, 4 * w, lane, acc);
    }
    __syncthreads();
    store_hilo(smem, lane, w, acc, true);   // gelu applied here
    __syncthreads();                        // h(hi/lo) ready

    // P4: layer 2 — out = h @ W2^T + b2
    {
        float b2v[4];
#pragma unroll
        for (int j = 0; j < 4; ++j) b2v[j] = b2[64 * w + 16 * j + (lane & 15)];
#pragma unroll
        for (int i = 0; i < 4; ++i)
#pragma unroll
            for (int j = 0; j < 4; ++j)
                acc[i][j] = (f32x4){b2v[j], b2v[j], b2v[j], b2v[j]};
        gemm_accum<16>(smem, 0, whi + 393216, wlo + 393216, 4 * w, lane, acc);
    }

    // Epilogue: fp32 store to global (lanes 0-15 cover 16 contiguous cols).
#pragma unroll
    for (int i = 0; i < 4; ++i) {
#pragma unroll
        for (int j = 0; j < 4; ++j) {
#pragma unroll
            for (int r = 0; r < 4; ++r) {
                int row = 16 * i + 4 * (lane >> 4) + r;
                int col = 64 * w + 16 * j + (lane & 15);
                out[(size_t)(tile * 64 + row) * AD + col] = acc[i][j][r];
            }
        }
    }
}

// ---------------------------------------------------------------------------
extern "C" void kernel_launch(void* const* d_in, const int* in_sizes, int n_in,
                              void* d_out, int out_size, void* d_ws, size_t ws_size,
                              hipStream_t stream) {
    const float* rel   = (const float*)d_in[0];
    const float* nodes = (const float*)d_in[1];
    const int*   eidx  = (const int*)d_in[2];
    const float* Wr    = (const float*)d_in[3];
    const float* Wn    = (const float*)d_in[4];
    const float* W1    = (const float*)d_in[5];
    const float* b1    = (const float*)d_in[6];
    const float* W2    = (const float*)d_in[7];
    const float* b2    = (const float*)d_in[8];
    float* out = (float*)d_out;

    short* whi = (short*)d_ws;            // 655360 shorts
    short* wlo = whi + 655360;            // 655360 shorts (total 2.62 MB of ws)

    prep_weights<<<320, 256, 0, stream>>>(Wr, Wn, W1, W2, whi, wlo);
    fused_kernel<<<N_WG, 512, 0, stream>>>(rel, nodes, eidx, whi, wlo, b1, b2, out);
}

// Round 8
// 1324.902 us; speedup vs baseline: 1.0110x; 1.0110x over previous
//
#include <hip/hip_runtime.h>
#include <hip/hip_bf16.h>
#include <math.h>

// Problem constants (from reference)
#define E_EDGES 200000
#define TD      256      // TOKEN_DIM
#define AD      512      // ACTION_DIM
#define M_TILE  64
#define N_WG    3125     // E / M_TILE exactly

// Weight workspace layout (in shorts): hi buffer then lo buffer.
//   Wr: [0, 65536)  Wn: [65536, 131072)  W1: [131072, 393216)  W2: [393216, 655360)
// Each matrix stored as MFMA B-fragment blobs: for (ntile, kstep):
//   lane l, elem i (0..7) = W[ntile*16 + (l&15)][kstep*32 + 8*(l>>4) + i]
// at short offset base + ((ntile*KS + kstep)*64 + l)*8 + i.
// Requires ws_size >= 2*655360*2 = 2.62 MB.

using short8  = __attribute__((ext_vector_type(8))) short;
using short4v = __attribute__((ext_vector_type(4))) short;
using f32x4   = __attribute__((ext_vector_type(4))) float;

__device__ __forceinline__ unsigned short f2bf(float x) {
    unsigned u = __float_as_uint(x);
    unsigned r = (u + 0x7fffu + ((u >> 16) & 1u)) >> 16;
    return (unsigned short)r;
}
__device__ __forceinline__ float bf2f(unsigned short h) {
    return __uint_as_float(((unsigned)h) << 16);
}

// byte offset into a [64][512]-short LDS tile, XOR-swizzled on bits 6-8.
// R7 fix: the old ^((r&7)<<4) collided with the k-group field (16*(lane>>4),
// also bits 4-6), collapsing each wave's A-fragment ds_read_b128 onto 8
// 16B slots -> 8-way bank conflict (3.2e7 conflict cycles measured).
// With ^((r&7)<<6): slot = g + 4*(ks ^ (r&7)) -> 32 distinct slots, 2
// lanes/slot (rows r, r+8) = conflict-free per m136.
__device__ __forceinline__ unsigned swz(int r, int c) {
    return (unsigned)((r * 512 + c) * 2) ^ (unsigned)((r & 7) << 6);
}

// ---------------------------------------------------------------------------
// Prep: fp32 weights -> bf16 hi/lo, pre-swizzled fragment layout in ws.
// 81920 blobs of 8 shorts each.
__global__ void prep_weights(const float* __restrict__ Wr, const float* __restrict__ Wn,
                             const float* __restrict__ W1, const float* __restrict__ W2,
                             short* __restrict__ whi, short* __restrict__ wlo) {
    int j = blockIdx.x * blockDim.x + threadIdx.x;
    if (j >= 81920) return;
    const float* W;
    int base_s, K, bj;
    if (j < 8192)       { W = Wr; base_s = 0;      K = 256; bj = j; }
    else if (j < 16384) { W = Wn; base_s = 65536;  K = 256; bj = j - 8192; }
    else if (j < 49152) { W = W1; base_s = 131072; K = 512; bj = j - 16384; }
    else                { W = W2; base_s = 393216; K = 512; bj = j - 49152; }
    int KS = K / 32;
    int l = bj & 63;
    int t = bj >> 6;
    int ks = t % KS;
    int ntile = t / KS;
    int n  = ntile * 16 + (l & 15);
    int kb = ks * 32 + 8 * (l >> 4);
    int off = base_s + bj * 8;   // == base_s + ((ntile*KS+ks)*64 + l)*8
#pragma unroll
    for (int i = 0; i < 8; ++i) {
        float x = W[(size_t)n * K + kb + i];
        unsigned short h  = f2bf(x);
        unsigned short lo = f2bf(x - bf2f(h));
        whi[off + i] = (short)h;
        wlo[off + i] = (short)lo;
    }
}

// ---------------------------------------------------------------------------
// One GEMM phase: acc += X_lds @ W^T using 3-product bf16 split.
// X hi at smem[0..64K), X lo at smem[64K..128K).
template <int KSTEPS>
__device__ __forceinline__ void gemm_accum(const char* smem, int xk_off,
                                           const short* __restrict__ bhi,
                                           const short* __restrict__ blo,
                                           int ntile_base, int lane,
                                           f32x4 acc[4][4]) {
    const short* pbh = bhi + (size_t)ntile_base * KSTEPS * 512 + (size_t)lane * 8;
    const short* pbl = blo + (size_t)ntile_base * KSTEPS * 512 + (size_t)lane * 8;
    for (int ks = 0; ks < KSTEPS; ++ks) {
        short8 ah[4], al[4];
        int kb = xk_off + ks * 32 + 8 * (lane >> 4);
#pragma unroll
        for (int i = 0; i < 4; ++i) {
            int row = 16 * i + (lane & 15);
            unsigned off = swz(row, kb);
            ah[i] = *(const short8*)(smem + off);
            al[i] = *(const short8*)(smem + 65536 + off);
        }
        short8 bh[4], bl[4];
#pragma unroll
        for (int j = 0; j < 4; ++j) {
            size_t wo = ((size_t)j * KSTEPS + ks) * 512;
            bh[j] = *(const short8*)(pbh + wo);
            bl[j] = *(const short8*)(pbl + wo);
        }
#pragma unroll
        for (int i = 0; i < 4; ++i) {
#pragma unroll
            for (int j = 0; j < 4; ++j) {
                acc[i][j] = __builtin_amdgcn_mfma_f32_16x16x32_bf16(ah[i], bh[j], acc[i][j], 0, 0, 0);
                acc[i][j] = __builtin_amdgcn_mfma_f32_16x16x32_bf16(ah[i], bl[j], acc[i][j], 0, 0, 0);
                acc[i][j] = __builtin_amdgcn_mfma_f32_16x16x32_bf16(al[i], bh[j], acc[i][j], 0, 0, 0);
            }
        }
    }
}

// Convert accumulators to hi/lo and store into LDS (C/D layout: col=lane&15,
// row=(lane>>4)*4+reg — m89-verified). Optional exact GELU first.
__device__ __forceinline__ void store_hilo(char* smem, int lane, int w,
                                           f32x4 acc[4][4], bool do_gelu) {
#pragma unroll
    for (int i = 0; i < 4; ++i) {
#pragma unroll
        for (int j = 0; j < 4; ++j) {
#pragma unroll
            for (int r = 0; r < 4; ++r) {
                float v = acc[i][j][r];
                if (do_gelu) v = 0.5f * v * (1.0f + erff(v * 0.7071067811865476f));
                int row = 16 * i + 4 * (lane >> 4) + r;
                int col = 64 * w + 16 * j + (lane & 15);
                unsigned short h  = f2bf(v);
                unsigned short lo = f2bf(v - bf2f(h));
                unsigned off = swz(row, col);
                *(unsigned short*)(smem + off)         = h;
                *(unsigned short*)(smem + 65536 + off) = lo;
            }
        }
    }
}

// ---------------------------------------------------------------------------
// Static LDS: 128 KiB X/activation hi+lo tile + 64 tail indices.
// (Static, not dynamic: >64KB dynamic LDS requires hipFuncSetAttribute;
//  static up to 160 KiB is allowed on gfx950.)
__global__ __launch_bounds__(512, 2) void fused_kernel(
    const float* __restrict__ rel, const float* __restrict__ nodes,
    const int* __restrict__ eidx, const short* __restrict__ whi,
    const short* __restrict__ wlo, const float* __restrict__ b1,
    const float* __restrict__ b2, float* __restrict__ out) {
    __shared__ __align__(16) char smem[131072];
    __shared__ int s_tail[64];
    const int tid  = threadIdx.x;
    const int tile = blockIdx.x;
    const int lane = tid & 63;
    const int w    = tid >> 6;

    if (tid < 64) s_tail[tid] = eidx[E_EDGES + tile * 64 + tid];
    __syncthreads();

    // P0: stage X = [R | gathered node] as bf16 hi/lo in LDS (swizzled).
#pragma unroll
    for (int c = 0; c < 16; ++c) {
        int g    = c * 512 + tid;
        int row  = g >> 7;        // 128 float4 per 512-col row
        int cf4  = g & 127;
        int e    = tile * 64 + row;
        float4 v;
        int col;
        if (cf4 < 64) {
            v   = *(const float4*)(rel + (size_t)e * TD + cf4 * 4);
            col = cf4 * 4;
        } else {
            int tail = s_tail[row];
            v   = *(const float4*)(nodes + (size_t)tail * TD + (cf4 - 64) * 4);
            col = 256 + (cf4 - 64) * 4;
        }
        float vv[4] = {v.x, v.y, v.z, v.w};
        short4v hv, lv;
#pragma unroll
        for (int t = 0; t < 4; ++t) {
            unsigned short hh = f2bf(vv[t]);
            hv[t] = (short)hh;
            lv[t] = (short)f2bf(vv[t] - bf2f(hh));
        }
        unsigned off = swz(row, col);
        *(short4v*)(smem + off)         = hv;
        *(short4v*)(smem + 65536 + off) = lv;
    }
    __syncthreads();

    // P1: layer 0 — ak[:,0:256)=R@Wr^T (waves 0-3), ak[:,256:512)=G@Wn^T (waves 4-7)
    f32x4 acc[4][4];
#pragma unroll
    for (int i = 0; i < 4; ++i)
#pragma unroll
        for (int j = 0; j < 4; ++j) acc[i][j] = (f32x4){0.f, 0.f, 0.f, 0.f};

    {
        int xoff = (w < 4) ? 0 : 256;
        const short* l0h = whi + ((w < 4) ? 0 : 65536);
        const short* l0l = wlo + ((w < 4) ? 0 : 65536);
        gemm_accum<8>(smem, xoff, l0h, l0l, 4 * (w & 3), lane, acc);
    }
    __syncthreads();                    // everyone done reading X
    store_hilo(smem, lane, w, acc, false);
    __syncthreads();                    // ak(hi/lo) ready

    // P3: layer 1 — h = gelu(ak @ W1^T + b1)
    {
        float b1v[4];
#pragma unroll
        for (int j = 0; j < 4; ++j) b1v[j] = b1[64 * w + 16 * j + (lane & 15)];
#pragma unroll
        for (int i = 0; i < 4; ++i)
#pragma unroll
            for (int j = 0; j < 4; ++j)
                acc[i][j] = (f32x4){b1v[j], b1v[j], b1v[j], b1v[j]};
        gemm_accum<16>(smem, 0, whi + 131072, wlo + 131072, 4 * w, lane, acc);
    }
    __syncthreads();
    store_hilo(smem, lane, w, acc, true);   // gelu applied here
    __syncthreads();                        // h(hi/lo) ready

    // P4: layer 2 — out = h @ W2^T + b2
    {
        float b2v[4];
#pragma unroll
        for (int j = 0; j < 4; ++j) b2v[j] = b2[64 * w + 16 * j + (lane & 15)];
#pragma unroll
        for (int i = 0; i < 4; ++i)
#pragma unroll
            for (int j = 0; j < 4; ++j)
                acc[i][j] = (f32x4){b2v[j], b2v[j], b2v[j], b2v[j]};
        gemm_accum<16>(smem, 0, whi + 393216, wlo + 393216, 4 * w, lane, acc);
    }

    // Epilogue: fp32 store to global (lanes 0-15 cover 16 contiguous cols).
#pragma unroll
    for (int i = 0; i < 4; ++i) {
#pragma unroll
        for (int j = 0; j < 4; ++j) {
#pragma unroll
            for (int r = 0; r < 4; ++r) {
                int row = 16 * i + 4 * (lane >> 4) + r;
                int col = 64 * w + 16 * j + (lane & 15);
                out[(size_t)(tile * 64 + row) * AD + col] = acc[i][j][r];
            }
        }
    }
}

// ---------------------------------------------------------------------------
extern "C" void kernel_launch(void* const* d_in, const int* in_sizes, int n_in,
                              void* d_out, int out_size, void* d_ws, size_t ws_size,
                              hipStream_t stream) {
    const float* rel   = (const float*)d_in[0];
    const float* nodes = (const float*)d_in[1];
    const int*   eidx  = (const int*)d_in[2];
    const float* Wr    = (const float*)d_in[3];
    const float* Wn    = (const float*)d_in[4];
    const float* W1    = (const float*)d_in[5];
    const float* b1    = (const float*)d_in[6];
    const float* W2    = (const float*)d_in[7];
    const float* b2    = (const float*)d_in[8];
    float* out = (float*)d_out;

    short* whi = (short*)d_ws;            // 655360 shorts
    short* wlo = whi + 655360;            // 655360 shorts (total 2.62 MB of ws)

    prep_weights<<<320, 256, 0, stream>>>(Wr, Wn, W1, W2, whi, wlo);
    fused_kernel<<<N_WG, 512, 0, stream>>>(rel, nodes, eidx, whi, wlo, b1, b2, out);
}